// Round 2
// baseline (90.069 us; speedup 1.0000x reference)
//
#include <hip/hip_runtime.h>

// 4-qubit, 2-layer QML circuit, B=1M samples, one thread/sample, state in regs.
// Amp index n = q0*8 + q1*4 + q2*2 + q3.
//
// Layer 1 on |0000>: product state v_q = RZ*RY*RX|0> = c_q*(P) + s_q*(Q) per
// component, weight-only constants precomputed. Tensor-expand to 16 amps,
// CNOT chain (register swaps, free).
// Layer 2: RZ dropped (diagonal phase followed only by basis permutation +
// |.|^2 => provably no effect on outputs). U = RY*RX, entries are signed
// combinations of p0=cy*c, p1=sy*s, p2=cy*s, p3=sy*c.
// Weight constants (40 floats) in d_ws, computed by tiny precompute kernel.

struct C2 { float r, i; };

__device__ __forceinline__ C2 cmul(C2 a, C2 b) {
    return C2{ a.r * b.r - a.i * b.i, a.r * b.i + a.i * b.r };
}

// g layout (40 floats):
//  l=0 qubit q: g[q*8 + 0..7] = Pr,Pi,Qr,Qi,Rr,Ri,Sr,Si  (v0 = c*(P)+s*(Q), v1 = c*(R)+s*(S))
//  l=1 qubit q: g[32 + q*2 + 0..1] = cy, sy
__global__ void precompute_gates(const float* __restrict__ w, float* __restrict__ g) {
    int t = threadIdx.x;  // 0..7 -> l*4 + q
    if (t >= 8) return;
    int l = t >> 2, q = t & 3;
    float thy = w[l * 8 + q * 2 + 0];
    float thz = w[l * 8 + q * 2 + 1];
    float cy = cosf(0.5f * thy), sy = sinf(0.5f * thy);
    float cz = cosf(0.5f * thz), sz = sinf(0.5f * thz);
    if (l == 0) {
        float* o = g + q * 8;
        o[0] = cz * cy;  o[1] = -sz * cy;
        o[2] = sz * sy;  o[3] =  cz * sy;
        o[4] = cz * sy;  o[5] =  sz * sy;
        o[6] = sz * cy;  o[7] = -cz * cy;
    } else {
        g[32 + q * 2 + 0] = cy;
        g[32 + q * 2 + 1] = sy;
    }
}

__device__ __forceinline__ void cnot_chain(C2 st[16]) {
    // CNOT(0,1): swap 8..11 <-> 12..15
    #pragma unroll
    for (int j = 0; j < 4; j++) { C2 t = st[8 + j]; st[8 + j] = st[12 + j]; st[12 + j] = t; }
    // CNOT(1,2): swap (4,6),(5,7),(12,14),(13,15)
    { C2 t;
      t = st[4];  st[4]  = st[6];  st[6]  = t;
      t = st[5];  st[5]  = st[7];  st[7]  = t;
      t = st[12]; st[12] = st[14]; st[14] = t;
      t = st[13]; st[13] = st[15]; st[15] = t; }
    // CNOT(2,3): swap (2,3),(6,7),(10,11),(14,15)
    { C2 t;
      t = st[2];  st[2]  = st[3];  st[3]  = t;
      t = st[6];  st[6]  = st[7];  st[7]  = t;
      t = st[10]; st[10] = st[11]; st[11] = t;
      t = st[14]; st[14] = st[15]; st[15] = t; }
}

// U = RY*RX = [[(p0,p1), (-p3,-p2)], [(p3,-p2), (p0,-p1)]]
__device__ __forceinline__ void apply_u(C2& a0, C2& a1,
                                        float p0, float p1, float p2, float p3) {
    C2 b0, b1;
    b0.r = p0 * a0.r - p1 * a0.i + p2 * a1.i - p3 * a1.r;
    b0.i = p0 * a0.i + p1 * a0.r - p2 * a1.r - p3 * a1.i;
    b1.r = p3 * a0.r + p2 * a0.i + p0 * a1.r + p1 * a1.i;
    b1.i = p3 * a0.i - p2 * a0.r + p0 * a1.i - p1 * a1.r;
    a0 = b0; a1 = b1;
}

__global__ void __launch_bounds__(256) qml_kernel(
        const float* __restrict__ x, const float* __restrict__ g,
        float* __restrict__ out, int batch) {
    int tid = blockIdx.x * blockDim.x + threadIdx.x;
    if (tid >= batch) return;

    float4 xv = reinterpret_cast<const float4*>(x)[tid];
    const float4* g4 = reinterpret_cast<const float4*>(g);

    // constants up front (uniform address -> L1/L2 broadcast-friendly)
    float4 G0 = g4[0], G1 = g4[1], G2 = g4[2], G3 = g4[3];
    float4 G4 = g4[4], G5 = g4[5], G6 = g4[6], G7 = g4[7];
    float4 W0 = g4[8], W1 = g4[9];

    // sin/cos of x/2 via raw v_sin/v_cos (input in revolutions: theta/(4*pi))
    const float K = 0.07957747154594767f;  // 1/(4*pi)
    float c0 = __builtin_amdgcn_cosf(K * xv.x), s0 = __builtin_amdgcn_sinf(K * xv.x);
    float c1 = __builtin_amdgcn_cosf(K * xv.y), s1 = __builtin_amdgcn_sinf(K * xv.y);
    float c2 = __builtin_amdgcn_cosf(K * xv.z), s2 = __builtin_amdgcn_sinf(K * xv.z);
    float c3 = __builtin_amdgcn_cosf(K * xv.w), s3 = __builtin_amdgcn_sinf(K * xv.w);

    // ---- layer 1: per-qubit 2-vectors ----
    C2 v[4][2];
    v[0][0] = C2{ c0 * G0.x + s0 * G0.z, c0 * G0.y + s0 * G0.w };
    v[0][1] = C2{ c0 * G1.x + s0 * G1.z, c0 * G1.y + s0 * G1.w };
    v[1][0] = C2{ c1 * G2.x + s1 * G2.z, c1 * G2.y + s1 * G2.w };
    v[1][1] = C2{ c1 * G3.x + s1 * G3.z, c1 * G3.y + s1 * G3.w };
    v[2][0] = C2{ c2 * G4.x + s2 * G4.z, c2 * G4.y + s2 * G4.w };
    v[2][1] = C2{ c2 * G5.x + s2 * G5.z, c2 * G5.y + s2 * G5.w };
    v[3][0] = C2{ c3 * G6.x + s3 * G6.z, c3 * G6.y + s3 * G6.w };
    v[3][1] = C2{ c3 * G7.x + s3 * G7.z, c3 * G7.y + s3 * G7.w };

    // ---- tensor expansion to 16 amps ----
    C2 t01[4], t23[4], st[16];
    #pragma unroll
    for (int a = 0; a < 2; a++)
        #pragma unroll
        for (int b = 0; b < 2; b++) {
            t01[a * 2 + b] = cmul(v[0][a], v[1][b]);
            t23[a * 2 + b] = cmul(v[2][a], v[3][b]);
        }
    #pragma unroll
    for (int a = 0; a < 4; a++)
        #pragma unroll
        for (int b = 0; b < 4; b++)
            st[a * 4 + b] = cmul(t01[a], t23[b]);

    cnot_chain(st);

    // ---- layer 2: U = RY*RX per qubit (RZ dropped: no effect on probs) ----
    {   // qubit 0, bit 8
        float p0 = W0.x * c0, p1 = W0.y * s0, p2 = W0.x * s0, p3 = W0.y * c0;
        #pragma unroll
        for (int n0 = 0; n0 < 16; n0++)
            if (!(n0 & 8)) apply_u(st[n0], st[n0 | 8], p0, p1, p2, p3);
    }
    {   // qubit 1, bit 4
        float p0 = W0.z * c1, p1 = W0.w * s1, p2 = W0.z * s1, p3 = W0.w * c1;
        #pragma unroll
        for (int n0 = 0; n0 < 16; n0++)
            if (!(n0 & 4)) apply_u(st[n0], st[n0 | 4], p0, p1, p2, p3);
    }
    {   // qubit 2, bit 2
        float p0 = W1.x * c2, p1 = W1.y * s2, p2 = W1.x * s2, p3 = W1.y * c2;
        #pragma unroll
        for (int n0 = 0; n0 < 16; n0++)
            if (!(n0 & 2)) apply_u(st[n0], st[n0 | 2], p0, p1, p2, p3);
    }
    {   // qubit 3, bit 1
        float p0 = W1.z * c3, p1 = W1.w * s3, p2 = W1.z * s3, p3 = W1.w * c3;
        #pragma unroll
        for (int n0 = 0; n0 < 16; n0++)
            if (!(n0 & 1)) apply_u(st[n0], st[n0 | 1], p0, p1, p2, p3);
    }

    cnot_chain(st);

    // ---- probabilities and <Z_i> ----
    float p[16];
    #pragma unroll
    for (int n = 0; n < 16; n++) p[n] = st[n].r * st[n].r + st[n].i * st[n].i;

    float a8[8], z3 = 0.f;
    #pragma unroll
    for (int m = 0; m < 8; m++) { a8[m] = p[2 * m] + p[2 * m + 1]; z3 += p[2 * m] - p[2 * m + 1]; }
    float b4[4], z2 = 0.f;
    #pragma unroll
    for (int k = 0; k < 4; k++) { b4[k] = a8[2 * k] + a8[2 * k + 1]; z2 += a8[2 * k] - a8[2 * k + 1]; }
    float z1 = (b4[0] - b4[1]) + (b4[2] - b4[3]);
    float z0 = (b4[0] + b4[1]) - (b4[2] + b4[3]);

    reinterpret_cast<float4*>(out)[tid] = make_float4(z0, z1, z2, z3);
}

extern "C" void kernel_launch(void* const* d_in, const int* in_sizes, int n_in,
                              void* d_out, int out_size, void* d_ws, size_t ws_size,
                              hipStream_t stream) {
    const float* x = (const float*)d_in[0];      // [B,4]
    const float* w = (const float*)d_in[1];      // [2,4,2]
    float* out = (float*)d_out;                  // [B,4]
    float* g = (float*)d_ws;                     // 40 floats of gate constants
    int batch = in_sizes[0] / 4;

    precompute_gates<<<1, 64, 0, stream>>>(w, g);
    int block = 256;
    int grid = (batch + block - 1) / block;
    qml_kernel<<<grid, block, 0, stream>>>(x, g, out, batch);
}

// Round 3
// 89.163 us; speedup vs baseline: 1.0102x; 1.0102x over previous
//
#include <hip/hip_runtime.h>

// 4-qubit, 2-layer QML circuit, B=1M samples, one thread/sample, state in regs.
// SINGLE fused kernel: each thread computes the 12 weight sin/cos pairs itself
// (uniform values, ~24 transcendental instrs) -- removes the precompute kernel,
// the g[] round-trip through memory, and the second graph node.
//
// Amp index n = q0*8 + q1*4 + q2*2 + q3.
// Layer 1 on |0000>: product state; v_q = RZ*RY*RX|0>:
//   v0 = ( c*czcy + s*szsy, -c*szcy + s*czsy )
//   v1 = ( c*czsy + s*szcy,  c*szsy - s*czcy )
// Tensor-expand to 16 amps, CNOT chain (register permutation, free).
// Layer 2: RZ dropped (diagonal phase followed only by basis permutation and
// |.|^2 => provably no effect on <Z_i>). U = RY*RX with entries built from
// p0=cy*c, p1=sy*s, p2=cy*s, p3=sy*c.

struct C2 { float r, i; };

__device__ __forceinline__ C2 cmul(C2 a, C2 b) {
    return C2{ a.r * b.r - a.i * b.i, a.r * b.i + a.i * b.r };
}

__device__ __forceinline__ void cnot_chain(C2 st[16]) {
    // CNOT(0,1): swap 8..11 <-> 12..15
    #pragma unroll
    for (int j = 0; j < 4; j++) { C2 t = st[8 + j]; st[8 + j] = st[12 + j]; st[12 + j] = t; }
    // CNOT(1,2): swap (4,6),(5,7),(12,14),(13,15)
    { C2 t;
      t = st[4];  st[4]  = st[6];  st[6]  = t;
      t = st[5];  st[5]  = st[7];  st[7]  = t;
      t = st[12]; st[12] = st[14]; st[14] = t;
      t = st[13]; st[13] = st[15]; st[15] = t; }
    // CNOT(2,3): swap (2,3),(6,7),(10,11),(14,15)
    { C2 t;
      t = st[2];  st[2]  = st[3];  st[3]  = t;
      t = st[6];  st[6]  = st[7];  st[7]  = t;
      t = st[10]; st[10] = st[11]; st[11] = t;
      t = st[14]; st[14] = st[15]; st[15] = t; }
}

// U = RY*RX = [[(p0,p1), (-p3,-p2)], [(p3,-p2), (p0,-p1)]]
__device__ __forceinline__ void apply_u(C2& a0, C2& a1,
                                        float p0, float p1, float p2, float p3) {
    C2 b0, b1;
    b0.r = p0 * a0.r - p1 * a0.i + p2 * a1.i - p3 * a1.r;
    b0.i = p0 * a0.i + p1 * a0.r - p2 * a1.r - p3 * a1.i;
    b1.r = p3 * a0.r + p2 * a0.i + p0 * a1.r + p1 * a1.i;
    b1.i = p3 * a0.i - p2 * a0.r + p0 * a1.i - p1 * a1.r;
    a0 = b0; a1 = b1;
}

__global__ void __launch_bounds__(256) qml_kernel(
        const float* __restrict__ x, const float* __restrict__ w,
        float* __restrict__ out, int batch) {
    int tid = blockIdx.x * blockDim.x + threadIdx.x;
    if (tid >= batch) return;

    const float K = 0.07957747154594767f;  // 1/(4*pi): theta/2 in revolutions

    // ---- weight angles (uniform across threads; scalar-cached loads) ----
    float4 wa = reinterpret_cast<const float4*>(w)[0];  // l0: q0(thy,thz) q1(thy,thz)
    float4 wb = reinterpret_cast<const float4*>(w)[1];  // l0: q2(thy,thz) q3(thy,thz)
    float4 wc = reinterpret_cast<const float4*>(w)[2];  // l1: q0(thy,thz) q1(thy,thz)
    float4 wd = reinterpret_cast<const float4*>(w)[3];  // l1: q2(thy,thz) q3(thy,thz)

    float cy1[4], sy1[4], cz1[4], sz1[4], cy2[4], sy2[4];
    {
        float thy[4] = { wa.x, wa.z, wb.x, wb.z };
        float thz[4] = { wa.y, wa.w, wb.y, wb.w };
        float thy2[4] = { wc.x, wc.z, wd.x, wd.z };
        #pragma unroll
        for (int q = 0; q < 4; q++) {
            cy1[q] = __builtin_amdgcn_cosf(K * thy[q]);
            sy1[q] = __builtin_amdgcn_sinf(K * thy[q]);
            cz1[q] = __builtin_amdgcn_cosf(K * thz[q]);
            sz1[q] = __builtin_amdgcn_sinf(K * thz[q]);
            cy2[q] = __builtin_amdgcn_cosf(K * thy2[q]);
            sy2[q] = __builtin_amdgcn_sinf(K * thy2[q]);
        }
    }

    // ---- per-sample data angles ----
    float4 xv = reinterpret_cast<const float4*>(x)[tid];
    float c[4], s[4];
    c[0] = __builtin_amdgcn_cosf(K * xv.x); s[0] = __builtin_amdgcn_sinf(K * xv.x);
    c[1] = __builtin_amdgcn_cosf(K * xv.y); s[1] = __builtin_amdgcn_sinf(K * xv.y);
    c[2] = __builtin_amdgcn_cosf(K * xv.z); s[2] = __builtin_amdgcn_sinf(K * xv.z);
    c[3] = __builtin_amdgcn_cosf(K * xv.w); s[3] = __builtin_amdgcn_sinf(K * xv.w);

    // ---- layer 1: per-qubit 2-vectors (product state) ----
    C2 v[4][2];
    #pragma unroll
    for (int q = 0; q < 4; q++) {
        float czcy = cz1[q] * cy1[q], szcy = sz1[q] * cy1[q];
        float czsy = cz1[q] * sy1[q], szsy = sz1[q] * sy1[q];
        v[q][0].r =  c[q] * czcy + s[q] * szsy;
        v[q][0].i = -c[q] * szcy + s[q] * czsy;
        v[q][1].r =  c[q] * czsy + s[q] * szcy;
        v[q][1].i =  c[q] * szsy - s[q] * czcy;
    }

    // ---- tensor expansion to 16 amps ----
    C2 t01[4], t23[4], st[16];
    #pragma unroll
    for (int a = 0; a < 2; a++)
        #pragma unroll
        for (int b = 0; b < 2; b++) {
            t01[a * 2 + b] = cmul(v[0][a], v[1][b]);
            t23[a * 2 + b] = cmul(v[2][a], v[3][b]);
        }
    #pragma unroll
    for (int a = 0; a < 4; a++)
        #pragma unroll
        for (int b = 0; b < 4; b++)
            st[a * 4 + b] = cmul(t01[a], t23[b]);

    cnot_chain(st);

    // ---- layer 2: U = RY*RX per qubit (RZ dropped: no effect on probs) ----
    #pragma unroll
    for (int q = 0; q < 4; q++) {
        float p0 = cy2[q] * c[q], p1 = sy2[q] * s[q];
        float p2 = cy2[q] * s[q], p3 = sy2[q] * c[q];
        int bit = 8 >> q;
        #pragma unroll
        for (int n0 = 0; n0 < 16; n0++)
            if (!(n0 & bit)) apply_u(st[n0], st[n0 | bit], p0, p1, p2, p3);
    }

    cnot_chain(st);

    // ---- probabilities and <Z_i> ----
    float p[16];
    #pragma unroll
    for (int n = 0; n < 16; n++) p[n] = st[n].r * st[n].r + st[n].i * st[n].i;

    float a8[8], z3 = 0.f;
    #pragma unroll
    for (int m = 0; m < 8; m++) { a8[m] = p[2 * m] + p[2 * m + 1]; z3 += p[2 * m] - p[2 * m + 1]; }
    float b4[4], z2 = 0.f;
    #pragma unroll
    for (int k = 0; k < 4; k++) { b4[k] = a8[2 * k] + a8[2 * k + 1]; z2 += a8[2 * k] - a8[2 * k + 1]; }
    float z1 = (b4[0] - b4[1]) + (b4[2] - b4[3]);
    float z0 = (b4[0] + b4[1]) - (b4[2] + b4[3]);

    reinterpret_cast<float4*>(out)[tid] = make_float4(z0, z1, z2, z3);
}

extern "C" void kernel_launch(void* const* d_in, const int* in_sizes, int n_in,
                              void* d_out, int out_size, void* d_ws, size_t ws_size,
                              hipStream_t stream) {
    const float* x = (const float*)d_in[0];      // [B,4]
    const float* w = (const float*)d_in[1];      // [2,4,2]
    float* out = (float*)d_out;                  // [B,4]
    int batch = in_sizes[0] / 4;

    int block = 256;
    int grid = (batch + block - 1) / block;
    qml_kernel<<<grid, block, 0, stream>>>(x, w, out, batch);
}